// Round 2
// baseline (640.111 us; speedup 1.0000x reference)
//
#include <hip/hip_runtime.h>

// ELBO for the chromatin "Decoding" model — round 2.
// Key change vs round 1: NO delta[N,G,32] materialization. Cuts are
// counting-sorted by g_d = cxg % G; a fused kernel (block per gene) holds the
// gene's 64x32 logit_weight in LDS (transposed, padded) and computes the
// 64-dot per component on the fly. Removes 253MB fetch + 640MB write +
// random 64B HBM gathers.

#define TPB 256
#define HALF_LOG_2PI 0.9189385332046727f

// 256-thread block reduction; valid in thread 0 only.
static __device__ __forceinline__ float block_reduce(float v) {
  #pragma unroll
  for (int off = 32; off > 0; off >>= 1) v += __shfl_down(v, off, 64);
  __shared__ float wsum[4];
  if ((threadIdx.x & 63) == 0) wsum[threadIdx.x >> 6] = v;
  __syncthreads();
  return (threadIdx.x == 0) ? (wsum[0] + wsum[1] + wsum[2] + wsum[3]) : 0.f;
}

// ---------------- A: gene params ----------------
__global__ __launch_bounds__(TPB) void gene_params_kernel(
    const int* __restrict__ genes_oi,
    const float* __restrict__ loc_w, const float* __restrict__ scale_w,
    const float* __restrict__ logit_w,
    float4* __restrict__ gp, int G) {
  int idx = blockIdx.x * TPB + threadIdx.x;       // over G*32
  if (idx >= G * 32) return;
  int g = idx >> 5, c = idx & 31;
  long long gene = genes_oi[g];
  float lv = loc_w[gene * 32 + c];
  float loc = 1.f / (1.f + __expf(-lv));
  float sc = 1e-5f + __expf(scale_w[gene * 32 + c]);
  gp[idx] = make_float4(loc, 1.f / sc, -__logf(sc) - HALF_LOG_2PI, logit_w[gene * 32 + c]);
}

// ---------------- S1: histogram of cuts over g_d ----------------
__global__ __launch_bounds__(TPB) void bin_hist_kernel(
    const int* __restrict__ cxg, unsigned* __restrict__ binCnt, int K, unsigned G) {
  int k = blockIdx.x * TPB + threadIdx.x;
  if (k >= K) return;
  unsigned ix = (unsigned)cxg[k];
  atomicAdd(&binCnt[ix % G], 1u);
}

// ---------------- S2: exclusive scan over G bins (single block) ----------------
__global__ __launch_bounds__(TPB) void scan_kernel(
    const unsigned* __restrict__ cnt, unsigned* __restrict__ offs,
    unsigned* __restrict__ cur, int G, int K) {
  __shared__ unsigned tmp[TPB];
  __shared__ unsigned base;
  if (threadIdx.x == 0) base = 0;
  __syncthreads();
  for (int c0 = 0; c0 < G; c0 += TPB) {
    int i = c0 + threadIdx.x;
    unsigned v = (i < G) ? cnt[i] : 0u;
    tmp[threadIdx.x] = v;
    __syncthreads();
    #pragma unroll
    for (int d = 1; d < TPB; d <<= 1) {
      unsigned t = (threadIdx.x >= (unsigned)d) ? tmp[threadIdx.x - d] : 0u;
      __syncthreads();
      tmp[threadIdx.x] += t;
      __syncthreads();
    }
    unsigned excl = tmp[threadIdx.x] - v + base;
    if (i < G) { offs[i] = excl; cur[i] = excl; }
    __syncthreads();
    if (threadIdx.x == TPB - 1) base = tmp[TPB - 1] + (base - 0) + 0, base = excl + v;  // base = last exclusive + last v
    __syncthreads();
  }
  if (threadIdx.x == 0) offs[G] = (unsigned)K;
}

// ---------------- S3: scatter cut indices into gene-sorted order ----------------
__global__ __launch_bounds__(TPB) void scatter_kernel(
    const int* __restrict__ cxg, unsigned* __restrict__ cur,
    int* __restrict__ sorted, int K, unsigned G) {
  int k = blockIdx.x * TPB + threadIdx.x;
  if (k >= K) return;
  unsigned ix = (unsigned)cxg[k];
  unsigned pos = atomicAdd(&cur[ix % G], 1u);
  sorted[pos] = k;
}

// ---------------- C: fragment-count histogram ----------------
__global__ __launch_bounds__(TPB) void hist_kernel(
    const int* __restrict__ lix, unsigned* __restrict__ counts, int F, long long NG) {
  int i = blockIdx.x * TPB + threadIdx.x;
  if (i >= F) return;
  long long v = lix[i];
  if (v >= 0 && v < NG) atomicAdd(&counts[v], 1u);
}

// ---------------- D: fused cuts (block per gene, W in LDS) ----------------
// Wt[c][l] padded to stride 68 floats: broadcast ds_read_b128, conflict-free.
__global__ __launch_bounds__(TPB) void cuts_fused_kernel(
    const float* __restrict__ xc, const int* __restrict__ gix,
    const int* __restrict__ cxg,
    const float* __restrict__ latent, const int* __restrict__ genes_oi,
    const float* __restrict__ logit_weight,
    const float4* __restrict__ gp,
    const unsigned* __restrict__ offs, const int* __restrict__ sorted,
    float* __restrict__ partials, int K, int G) {
  int g = blockIdx.x;
  __shared__ __align__(16) float Wt[32 * 68];
  {
    long long gene = genes_oi[g];
    const float* W = logit_weight + gene * 2048;
    for (int t = threadIdx.x; t < 2048; t += TPB) {
      int l = t >> 5, c = t & 31;
      Wt[c * 68 + l] = W[t];
    }
  }
  __syncthreads();
  unsigned start = offs[g], end = offs[g + 1];
  float lm = 0.f;
  for (unsigned kk = start + threadIdx.x; kk < end; kk += TPB) {
    int k = sorted[kk];
    float x = xc[k];
    unsigned ix = (unsigned)cxg[k];
    unsigned n_d = ix / (unsigned)G;
    const float4* lat4 = (const float4*)(latent + (size_t)n_d * 64);
    float4 lat[16];
    #pragma unroll
    for (int i = 0; i < 16; i++) lat[i] = lat4[i];
    const float4* gpr = gp + (long long)gix[k] * 32;
    float s1 = 0.f, s2 = 0.f;
    #pragma unroll 8
    for (int c = 0; c < 32; c++) {
      const float4* wrow = (const float4*)(&Wt[c * 68]);
      float acc = 0.f;
      #pragma unroll
      for (int i = 0; i < 16; i++) {
        float4 w = wrow[i];
        acc = fmaf(lat[i].x, w.x, acc);
        acc = fmaf(lat[i].y, w.y, acc);
        acc = fmaf(lat[i].z, w.z, acc);
        acc = fmaf(lat[i].w, w.w, acc);
      }
      float4 p = gpr[c];
      float t0 = p.w + acc;
      float z = (x - p.x) * p.y;
      float u = t0 + fmaf(-0.5f * z, z, p.z);
      s1 += __expf(u);
      s2 += __expf(t0);
    }
    lm += __logf(s1) - __logf(s2);
  }
  float bs = block_reduce(lm);
  if (threadIdx.x == 0) partials[blockIdx.x] = bs;
}

// ---------------- E: Poisson fragment counts ----------------
__global__ __launch_bounds__(TPB) void pois_kernel(
    const float* __restrict__ latent, const int* __restrict__ genes_oi,
    const int* __restrict__ cells_oi,
    const float* __restrict__ rho_weight, const float* __restrict__ rho_bias,
    const float* __restrict__ libsize,
    const unsigned* __restrict__ counts,
    float* __restrict__ partials, int N, int G) {
  int g = blockIdx.x * TPB + threadIdx.x;
  int n0 = blockIdx.y * 8;
  float sum = 0.f;
  if (g < G) {
    long long gene = genes_oi[g];
    const float4* rw = (const float4*)(rho_weight + gene * 64);
    float rho[8];
    #pragma unroll
    for (int j = 0; j < 8; j++) rho[j] = 0.f;
    #pragma unroll
    for (int l4 = 0; l4 < 16; l4++) {
      float4 w = rw[l4];
      #pragma unroll
      for (int j = 0; j < 8; j++) {
        int n = n0 + j;
        if (n < N) {
          float4 lv = *(const float4*)(latent + (size_t)n * 64 + l4 * 4);
          rho[j] += w.x * lv.x + w.y * lv.y + w.z * lv.z + w.w * lv.w;
        }
      }
    }
    float rb = rho_bias[gene];
    #pragma unroll
    for (int j = 0; j < 8; j++) {
      int n = n0 + j;
      if (n >= N) break;
      float lib = libsize[cells_oi[n]];
      float fe = rb * __expf(rho[j]) * lib;
      unsigned cnt = counts[(size_t)n * G + g];
      float term = -fe;
      if (cnt) {
        float lf = 0.f;
        for (unsigned q = 2; q <= cnt; q++) lf += __logf((float)q);
        term += (float)cnt * __logf(fe) - lf;
      }
      sum += term;
    }
  }
  float bs = block_reduce(sum);
  if (threadIdx.x == 0) partials[blockIdx.y * gridDim.x + blockIdx.x] = bs;
}

// ---------------- F: finalize ----------------
__global__ __launch_bounds__(TPB) void finalize_kernel(
    const float* __restrict__ p1, int n1,
    const float* __restrict__ p2, int n2, float* __restrict__ out) {
  float s = 0.f;
  for (int i = threadIdx.x; i < n1; i += TPB) s += p1[i];
  for (int i = threadIdx.x; i < n2; i += TPB) s += p2[i];
  float bs = block_reduce(s);
  if (threadIdx.x == 0) out[0] = -bs;
}

extern "C" void kernel_launch(void* const* d_in, const int* in_sizes, int n_in,
                              void* d_out, int out_size, void* d_ws, size_t ws_size,
                              hipStream_t stream) {
  const int*   lix          = (const int*)d_in[0];
  const float* xc           = (const float*)d_in[1];
  const float* latent       = (const float*)d_in[2];
  const int*   genes_oi     = (const int*)d_in[3];
  const int*   cells_oi     = (const int*)d_in[4];
  const int*   cxg          = (const int*)d_in[5];
  const int*   gix          = (const int*)d_in[6];
  const float* loc_w        = (const float*)d_in[9];
  const float* scale_w      = (const float*)d_in[10];
  const float* logit_w      = (const float*)d_in[11];
  const float* logit_weight = (const float*)d_in[12];
  const float* rho_weight   = (const float*)d_in[13];
  const float* rho_bias     = (const float*)d_in[14];
  const float* libsize      = (const float*)d_in[15];
  float* out = (float*)d_out;

  const int F = in_sizes[0];
  const int K = in_sizes[1];
  const int N = in_sizes[2] / 64;
  const int G = in_sizes[3];
  const long long NG = (long long)N * G;

  const int gpx = (G + TPB - 1) / TPB;
  const int npy = (N + 7) / 8;
  const int npb = gpx * npy;

  size_t off = 0;
  auto alloc = [&](size_t bytes) {
    size_t o = off;
    off = (off + bytes + 255) & ~(size_t)255;
    return o;
  };
  size_t counts_off = alloc((size_t)NG * 4);
  size_t gp_off     = alloc((size_t)G * 32 * 16);
  size_t bin_off    = alloc((size_t)G * 4);
  size_t offs_off   = alloc((size_t)(G + 1) * 4);
  size_t cur_off    = alloc((size_t)G * 4);
  size_t sort_off   = alloc((size_t)K * 4);
  size_t p1_off     = alloc((size_t)G * 4);
  size_t p2_off     = alloc((size_t)npb * 4);
  (void)ws_size;  // ~14.5 MB needed; harness provides far more

  char* ws = (char*)d_ws;
  unsigned* counts = (unsigned*)(ws + counts_off);
  float4* gp       = (float4*)(ws + gp_off);
  unsigned* binCnt = (unsigned*)(ws + bin_off);
  unsigned* offs   = (unsigned*)(ws + offs_off);
  unsigned* cur    = (unsigned*)(ws + cur_off);
  int* sorted      = (int*)(ws + sort_off);
  float* p1        = (float*)(ws + p1_off);
  float* p2        = (float*)(ws + p2_off);

  hipMemsetAsync(counts, 0, (size_t)NG * 4, stream);
  hipMemsetAsync(binCnt, 0, (size_t)G * 4, stream);

  gene_params_kernel<<<(G * 32 + TPB - 1) / TPB, TPB, 0, stream>>>(
      genes_oi, loc_w, scale_w, logit_w, gp, G);
  bin_hist_kernel<<<(K + TPB - 1) / TPB, TPB, 0, stream>>>(cxg, binCnt, K, (unsigned)G);
  scan_kernel<<<1, TPB, 0, stream>>>(binCnt, offs, cur, G, K);
  scatter_kernel<<<(K + TPB - 1) / TPB, TPB, 0, stream>>>(cxg, cur, sorted, K, (unsigned)G);
  hist_kernel<<<(F + TPB - 1) / TPB, TPB, 0, stream>>>(lix, counts, F, NG);
  cuts_fused_kernel<<<G, TPB, 0, stream>>>(xc, gix, cxg, latent, genes_oi,
                                           logit_weight, gp, offs, sorted, p1, K, G);
  dim3 pgrid(gpx, npy);
  pois_kernel<<<pgrid, TPB, 0, stream>>>(latent, genes_oi, cells_oi, rho_weight,
                                         rho_bias, libsize, counts, p2, N, G);
  finalize_kernel<<<1, TPB, 0, stream>>>(p1, G, p2, npb, out);
}